// Round 13
// baseline (300.948 us; speedup 1.0000x reference)
//
#include <hip/hip_runtime.h>
#include <hip/hip_bf16.h>
#include <cstdint>
#include <cstddef>
#include <type_traits>

#define HID 1024
#define HEADS 8
#define HDIM 128
#define SEQ 4096
#define BATCH 2

typedef float f32x4 __attribute__((ext_vector_type(4)));
typedef float f32x16 __attribute__((ext_vector_type(16)));
typedef short bf16x8 __attribute__((ext_vector_type(8)));
typedef unsigned short u16x8 __attribute__((ext_vector_type(8)));

typedef bf16x8 __attribute__((may_alias)) bf16x8_a;
typedef u16x8  __attribute__((may_alias)) u16x8_a;
typedef float4 __attribute__((may_alias)) float4_a;
typedef unsigned int __attribute__((may_alias)) u32_a;

__device__ __forceinline__ unsigned short f2bf(float f) {
    union { float f; unsigned int u; } v; v.f = f;
    unsigned int u = v.u;
    unsigned int r = (u + 0x7FFFu + ((u >> 16) & 1u)) >> 16;
    return (unsigned short)r;
}
__device__ __forceinline__ float bf2f(unsigned short h) {
    union { unsigned int u; float f; } v; v.u = ((unsigned int)h) << 16;
    return v.f;
}

__device__ __forceinline__ void plane_swap(unsigned int& x, unsigned int& y) {
    // swaps x's high 32 lanes with y's low 32 lanes
    asm("v_permlane32_swap_b32 %0, %1" : "+v"(x), "+v"(y));
}
__device__ __forceinline__ unsigned int cvt_pk(float lo, float hi) {
    unsigned int r;
    asm("v_cvt_pk_bf16_f32 %0, %1, %2" : "=v"(r) : "v"(lo), "v"(hi));
    return r;
}
__device__ __forceinline__ bf16x8 pack4(unsigned int a, unsigned int b,
                                        unsigned int c, unsigned int d) {
    union { unsigned int u[4]; bf16x8 v; } t;
    t.u[0] = a; t.u[1] = b; t.u[2] = c; t.u[3] = d;
    return t.v;
}
__device__ __forceinline__ void g2lds16(const unsigned short* g, unsigned short* l) {
    __builtin_amdgcn_global_load_lds(
        (const __attribute__((address_space(1))) void*)g,
        (__attribute__((address_space(3))) void*)l, 16, 0, 0);
}

// f32 -> bf16 bulk convert, 8 elems/thread
__global__ __launch_bounds__(256)
void cvt_kernel(const float* __restrict__ X, unsigned short* __restrict__ Y)
{
    int i = (blockIdx.x * 256 + threadIdx.x) * 8;
    float4 d0 = *(const float4_a*)&X[i];
    float4 d1 = *(const float4_a*)&X[i + 4];
    u16x8 t;
    t[0] = f2bf(d0.x); t[1] = f2bf(d0.y); t[2] = f2bf(d0.z); t[3] = f2bf(d0.w);
    t[4] = f2bf(d1.x); t[5] = f2bf(d1.y); t[6] = f2bf(d1.z); t[7] = f2bf(d1.w);
    *(u16x8_a*)&Y[i] = t;
}

// Primary GEMM: C[M,N] = A[M,K]*B[N,K]^T, both bf16, staged via global_load_lds
// (m97 pattern: linear LDS dest, width-16 async copies).
template<typename OutT>
__global__ __launch_bounds__(256)
void gemm_lds(const unsigned short* __restrict__ A, const unsigned short* __restrict__ B,
              OutT* __restrict__ C, int M, int N, int K)
{
    __shared__ __align__(16) unsigned short Al[128][64];
    __shared__ __align__(16) unsigned short Bl[128][64];
    const int tid  = threadIdx.x;
    const int lane = tid & 63;
    const int w    = tid >> 6;
    const int wr   = w >> 1, wc = w & 1;
    const int l16  = lane & 15, l4 = lane >> 4;
    const int tm   = blockIdx.y * 128, tn = blockIdx.x * 128;
    const int lrow = lane >> 3, lcol = (lane & 7) * 8;

    f32x4 acc[4][4] = {};

    for (int ko = 0; ko < K; ko += 64) {
        __syncthreads();
#pragma unroll
        for (int it = 0; it < 4; ++it) {
            int ca = w * 4 + it;            // chunk 0..15 (8 rows each)
            int row = ca * 8 + lrow;
            g2lds16(&A[(size_t)(tm + row) * K + ko + lcol], &Al[ca * 8][0]);
            g2lds16(&B[(size_t)(tn + row) * K + ko + lcol], &Bl[ca * 8][0]);
        }
        __syncthreads();
#pragma unroll
        for (int kk = 0; kk < 2; ++kk) {
            bf16x8 af[4], bfr[4];
#pragma unroll
            for (int i = 0; i < 4; ++i)
                af[i] = *(const bf16x8_a*)&Al[wr*64 + i*16 + l16][kk*32 + l4*8];
#pragma unroll
            for (int j = 0; j < 4; ++j)
                bfr[j] = *(const bf16x8_a*)&Bl[wc*64 + j*16 + l16][kk*32 + l4*8];
#pragma unroll
            for (int i = 0; i < 4; ++i)
#pragma unroll
                for (int j = 0; j < 4; ++j)
                    acc[i][j] = __builtin_amdgcn_mfma_f32_16x16x32_bf16(af[i], bfr[j], acc[i][j], 0, 0, 0);
        }
    }
#pragma unroll
    for (int i = 0; i < 4; ++i)
#pragma unroll
        for (int j = 0; j < 4; ++j)
#pragma unroll
            for (int r = 0; r < 4; ++r) {
                int row = tm + wr*64 + i*16 + l4*4 + r;
                int col = tn + wc*64 + j*16 + l16;
                if constexpr (std::is_same<OutT, float>::value)
                    C[(size_t)row * N + col] = acc[i][j][r];
                else
                    C[(size_t)row * N + col] = f2bf(acc[i][j][r]);
            }
}

// Fallback GEMM (reg-staged, f32 or bf16 operands).
template<bool A_BF16, bool B_BF16, typename OutT>
__global__ __launch_bounds__(256)
void gemm_bt(const void* __restrict__ Av, const void* __restrict__ Bv,
             OutT* __restrict__ C, int M, int N, int K)
{
    __shared__ __align__(16) unsigned short Al[128][72];
    __shared__ __align__(16) unsigned short Bl[128][72];
    const int tid  = threadIdx.x;
    const int lane = tid & 63;
    const int w    = tid >> 6;
    const int wr   = w >> 1, wc = w & 1;
    const int l16  = lane & 15, l4 = lane >> 4;
    const int tm   = blockIdx.y * 128, tn = blockIdx.x * 128;

    f32x4 acc[4][4] = {};

    for (int ko = 0; ko < K; ko += 64) {
        __syncthreads();
#pragma unroll
        for (int it = 0; it < 4; ++it) {
            int c = tid + 256 * it;
            int row = c >> 3, col0 = (c & 7) * 8;
            if constexpr (A_BF16) {
                const unsigned short* A = (const unsigned short*)Av;
                *(u16x8_a*)&Al[row][col0] =
                    *(const u16x8_a*)&A[(size_t)(tm + row) * K + ko + col0];
            } else {
                const float* A = (const float*)Av;
                const float* p = &A[(size_t)(tm + row) * K + ko + col0];
                float4 d0 = *(const float4_a*)p;
                float4 d1 = *(const float4_a*)(p + 4);
                u16x8 t;
                t[0] = f2bf(d0.x); t[1] = f2bf(d0.y); t[2] = f2bf(d0.z); t[3] = f2bf(d0.w);
                t[4] = f2bf(d1.x); t[5] = f2bf(d1.y); t[6] = f2bf(d1.z); t[7] = f2bf(d1.w);
                *(u16x8_a*)&Al[row][col0] = t;
            }
            if constexpr (B_BF16) {
                const unsigned short* B = (const unsigned short*)Bv;
                *(u16x8_a*)&Bl[row][col0] =
                    *(const u16x8_a*)&B[(size_t)(tn + row) * K + ko + col0];
            } else {
                const float* B = (const float*)Bv;
                const float* p = &B[(size_t)(tn + row) * K + ko + col0];
                float4 d0 = *(const float4_a*)p;
                float4 d1 = *(const float4_a*)(p + 4);
                u16x8 t;
                t[0] = f2bf(d0.x); t[1] = f2bf(d0.y); t[2] = f2bf(d0.z); t[3] = f2bf(d0.w);
                t[4] = f2bf(d1.x); t[5] = f2bf(d1.y); t[6] = f2bf(d1.z); t[7] = f2bf(d1.w);
                *(u16x8_a*)&Bl[row][col0] = t;
            }
        }
        __syncthreads();
#pragma unroll
        for (int kk = 0; kk < 2; ++kk) {
            bf16x8 af[4], bfr[4];
#pragma unroll
            for (int i = 0; i < 4; ++i)
                af[i] = *(const bf16x8_a*)&Al[wr*64 + i*16 + l16][kk*32 + l4*8];
#pragma unroll
            for (int j = 0; j < 4; ++j)
                bfr[j] = *(const bf16x8_a*)&Bl[wc*64 + j*16 + l16][kk*32 + l4*8];
#pragma unroll
            for (int i = 0; i < 4; ++i)
#pragma unroll
                for (int j = 0; j < 4; ++j)
                    acc[i][j] = __builtin_amdgcn_mfma_f32_16x16x32_bf16(af[i], bfr[j], acc[i][j], 0, 0, 0);
        }
    }
#pragma unroll
    for (int i = 0; i < 4; ++i)
#pragma unroll
        for (int j = 0; j < 4; ++j)
#pragma unroll
            for (int r = 0; r < 4; ++r) {
                int row = tm + wr*64 + i*16 + l4*4 + r;
                int col = tn + wc*64 + j*16 + l16;
                if constexpr (std::is_same<OutT, float>::value)
                    C[(size_t)row * N + col] = acc[i][j][r];
                else
                    C[(size_t)row * N + col] = f2bf(acc[i][j][r]);
            }
}

// In-place RoPE on bf16 (B,L,H,D); interleaved pairs (2i, 2i+1).
__global__ __launch_bounds__(256)
void rope_kernel(unsigned short* __restrict__ X, const int* __restrict__ pos_ids)
{
    int c = blockIdx.x * 256 + threadIdx.x;
    int d0 = (c & 15) * 8;
    int h  = (c >> 4) & 7;
    int l  = (c >> 7) & 4095;
    int b  = c >> 19;
    int pos = pos_ids[b * SEQ + l];
    size_t off = ((size_t)(b * SEQ + l) * HEADS + h) * HDIM + d0;
    u16x8 d = *(const u16x8_a*)&X[off];
    float x[8];
#pragma unroll
    for (int j = 0; j < 8; ++j) x[j] = bf2f(d[j]);
#pragma unroll
    for (int j = 0; j < 4; ++j) {
        int i = (d0 >> 1) + j;
        float invf = powf(10000.0f, -(float)i * (1.0f / 64.0f));
        float ang = (float)pos * invf;
        float s, cth;
        sincosf(ang, &s, &cth);
        float o0 = x[2*j] * cth - x[2*j+1] * s;
        float o1 = x[2*j] * s   + x[2*j+1] * cth;
        d[2*j]   = f2bf(o0);
        d[2*j+1] = f2bf(o1);
    }
    *(u16x8_a*)&X[off] = d;
}

// Flash attention, BLOCK-causal (2048) + segment mask (sorted 0->1: mask ==
// (key<boundary)==(q<boundary)), with segment skip. grid (SEQ/128, H, B),
// 256 threads = 4 waves x 32 q. SWAPPED QK^T: mfma(K,Q) -> lane l32 holds
// P[q=l32][keys in regs]; P routed to PV A-frags in-register via
// v_cvt_pk_bf16_f32 + v_permlane32_swap (no P LDS). lsum in-register.
// O aliases Q (in-place).
__global__ __launch_bounds__(256, 3)
void attn_kernel(const unsigned short* Q,
                 const unsigned short* K,
                 const unsigned short* V,
                 const int* __restrict__ seg,
                 unsigned short* O)
{
    __shared__ __align__(16) unsigned short Kl[64][136];
    __shared__ __align__(16) unsigned short Vt[128][72];

    const int tid  = threadIdx.x;
    const int lane = tid & 63;
    const int w    = tid >> 6;
    const int l32  = lane & 31, hi = lane >> 5;
    const int qt = (SEQ / 128 - 1) - blockIdx.x;
    const int h  = blockIdx.y;
    const int b  = blockIdx.z;
    const int qg0 = qt * 128 + w * 32;

    // Q fragments (B-operand of swapped QK^T): Q[q=l32][d=kk*16+hi*8+e]
    bf16x8 qf[8];
    {
        size_t base = ((size_t)(b * SEQ + qg0 + l32) * HEADS + h) * HDIM;
#pragma unroll
        for (int kk = 0; kk < 8; ++kk)
            qf[kk] = *(const bf16x8_a*)&Q[base + kk*16 + hi*8];
    }

    f32x16 acco0 = {}, acco1 = {}, acco2 = {}, acco3 = {};
    float lsum = 0.f;

    const int nkt = ((qt >> 4) + 1) * 32;   // block-causal (2048-token blocks)

    // segment boundary (first seg1 index), wave-uniform
    int lo = 0, hb = SEQ;
    while (lo < hb) { int mid = (lo + hb) >> 1; if (seg[b * SEQ + mid] == 0) lo = mid + 1; else hb = mid; }
    const int boundary = lo;
    int kstart = 0, kend = nkt;
    if (seg[b * SEQ + qt * 128] == 1) kstart = boundary >> 6;
    if (seg[b * SEQ + qt * 128 + 127] == 0) {
        int ke = (boundary + 63) >> 6;
        kend = ke < nkt ? ke : nkt;
    }
    const bool qlt = (qg0 + l32) < boundary;

    const int kp = tid & 31, db = tid >> 5;
    const float sc = 0.08838834764831845f;   // 1/sqrt(128)

    for (int kt = kstart; kt < kend; ++kt) {
        const int kb = kt * 64;
        __syncthreads();
        // ---- stage K (coalesced) ----
#pragma unroll
        for (int it = 0; it < 4; ++it) {
            int c = tid + 256 * it;
            u16x8 kd = *(const u16x8_a*)&K[((size_t)(b * SEQ + kb + (c >> 4)) * HEADS + h) * HDIM + (c & 15) * 8];
            *(u16x8_a*)&Kl[c >> 4][(c & 15) * 8] = kd;
        }
        // ---- stage V transposed (u32 key-pair packing) ----
        {
            size_t vb0 = ((size_t)(b * SEQ + kb + 2 * kp) * HEADS + h) * HDIM + db * 16;
            size_t vb1 = ((size_t)(b * SEQ + kb + 2 * kp + 1) * HEADS + h) * HDIM + db * 16;
            u16x8 v0a = *(const u16x8_a*)&V[vb0];
            u16x8 v0b = *(const u16x8_a*)&V[vb0 + 8];
            u16x8 v1a = *(const u16x8_a*)&V[vb1];
            u16x8 v1b = *(const u16x8_a*)&V[vb1 + 8];
#pragma unroll
            for (int j = 0; j < 8; ++j) {
                *(u32_a*)&Vt[db * 16 + j][2 * kp] =
                    (unsigned int)(unsigned short)v0a[j] | ((unsigned int)(unsigned short)v1a[j] << 16);
                *(u32_a*)&Vt[db * 16 + 8 + j][2 * kp] =
                    (unsigned int)(unsigned short)v0b[j] | ((unsigned int)(unsigned short)v1b[j] << 16);
            }
        }
        __syncthreads();

        // ---- two 32-key tiles: swapped QK^T -> in-reg P -> PV ----
#pragma unroll
        for (int t = 0; t < 2; ++t) {
            f32x16 a = {};
#pragma unroll
            for (int kk = 0; kk < 8; ++kk) {
                bf16x8 kf = *(const bf16x8_a*)&Kl[t*32 + l32][kk*16 + hi*8];
                a = __builtin_amdgcn_mfma_f32_32x32x16_bf16(kf, qf[kk], a, 0, 0, 0);
            }
            // mask + exp + pack: reg r -> key kb + t*32 + (r&3)+8*(r>>2)+4*hi
            unsigned int pk[8];
            const int keybase = kb + t * 32 + 4 * hi;
#pragma unroll
            for (int i = 0; i < 8; ++i) {
                int r0 = 2 * i;
                int key0 = keybase + (r0 & 3) + 8 * (r0 >> 2);
                float p0 = ((key0     < boundary) == qlt) ? __expf(a[r0]     * sc) : 0.0f;
                float p1 = ((key0 + 1 < boundary) == qlt) ? __expf(a[r0 + 1] * sc) : 0.0f;
                lsum += p0 + p1;
                pk[i] = cvt_pk(p0, p1);
            }
            // route halves: after swaps, frag(chunk c)=[pk4c..pk4c+3]
            plane_swap(pk[0], pk[2]); plane_swap(pk[1], pk[3]);
            plane_swap(pk[4], pk[6]); plane_swap(pk[5], pk[7]);
#pragma unroll
            for (int cc = 0; cc < 2; ++cc) {
                bf16x8 pf = pack4(pk[cc*4], pk[cc*4+1], pk[cc*4+2], pk[cc*4+3]);
                const int ks = t * 2 + cc;
                bf16x8 vf0 = *(const bf16x8_a*)&Vt[      l32][ks*16 + hi*8];
                bf16x8 vf1 = *(const bf16x8_a*)&Vt[32  + l32][ks*16 + hi*8];
                bf16x8 vf2 = *(const bf16x8_a*)&Vt[64  + l32][ks*16 + hi*8];
                bf16x8 vf3 = *(const bf16x8_a*)&Vt[96  + l32][ks*16 + hi*8];
                acco0 = __builtin_amdgcn_mfma_f32_32x32x16_bf16(pf, vf0, acco0, 0, 0, 0);
                acco1 = __builtin_amdgcn_mfma_f32_32x32x16_bf16(pf, vf1, acco1, 0, 0, 0);
                acco2 = __builtin_amdgcn_mfma_f32_32x32x16_bf16(pf, vf2, acco2, 0, 0, 0);
                acco3 = __builtin_amdgcn_mfma_f32_32x32x16_bf16(pf, vf3, acco3, 0, 0, 0);
            }
        }
    }

    // ---- epilogue ----
    float tot = lsum + __shfl_xor(lsum, 32, 64);   // full row-sum for q=l32
#pragma unroll
    for (int r = 0; r < 16; ++r) {
        int qrow = (r & 3) + 8 * (r >> 2) + 4 * hi;
        float inv = 1.0f / __shfl(tot, qrow, 64);
        size_t base = ((size_t)(b * SEQ + qg0 + qrow) * HEADS + h) * HDIM;
        O[base +       l32] = f2bf(acco0[r] * inv);
        O[base +  32 + l32] = f2bf(acco1[r] * inv);
        O[base +  64 + l32] = f2bf(acco2[r] * inv);
        O[base +  96 + l32] = f2bf(acco3[r] * inv);
    }
}

extern "C" void kernel_launch(void* const* d_in, const int* in_sizes, int n_in,
                              void* d_out, int out_size, void* d_ws, size_t ws_size,
                              hipStream_t stream)
{
    const float* X  = (const float*)d_in[0];
    const float* wq = (const float*)d_in[1];
    const float* wk = (const float*)d_in[2];
    const float* wv = (const float*)d_in[3];
    const float* wo = (const float*)d_in[4];
    const int* seg = (const int*)d_in[n_in - 2];
    const int* pos = (const int*)d_in[n_in - 1];
    float* out = (float*)d_out;

    const size_t NTOK = (size_t)BATCH * SEQ;        // 8192
    const size_t MAT  = NTOK * HID;                 // 8.39M elems
    const size_t WSZ  = (size_t)HID * HID;          // 1.05M elems

    unsigned short* Qb = (unsigned short*)d_ws;
    unsigned short* Kb = Qb + MAT;
    unsigned short* Vb = Kb + MAT;
    unsigned short* Xb = Vb + MAT;
    unsigned short* Wqb = Xb + MAT;
    unsigned short* Wkb = Wqb + WSZ;
    unsigned short* Wvb = Wkb + WSZ;
    unsigned short* Wob = Wvb + WSZ;

    dim3 gg(HID / 128, (int)(NTOK / 128));          // (8, 64)
    dim3 ga(SEQ / 128, HEADS, BATCH);               // (32, 8, 2)
    const int wcvt = (int)(WSZ / (256 * 8));

    if (ws_size >= (4 * MAT + 4 * WSZ) * sizeof(unsigned short)) {
        cvt_kernel<<<(int)(MAT / (256 * 8)), 256, 0, stream>>>(X, Xb);
        cvt_kernel<<<wcvt, 256, 0, stream>>>(wq, Wqb);
        cvt_kernel<<<wcvt, 256, 0, stream>>>(wk, Wkb);
        cvt_kernel<<<wcvt, 256, 0, stream>>>(wv, Wvb);
        cvt_kernel<<<wcvt, 256, 0, stream>>>(wo, Wob);
        gemm_lds<unsigned short><<<gg, 256, 0, stream>>>(Xb, Wqb, Qb, (int)NTOK, HID, HID);
        gemm_lds<unsigned short><<<gg, 256, 0, stream>>>(Xb, Wkb, Kb, (int)NTOK, HID, HID);
        gemm_lds<unsigned short><<<gg, 256, 0, stream>>>(Xb, Wvb, Vb, (int)NTOK, HID, HID);

        rope_kernel<<<(BATCH * SEQ * HEADS * 16) / 256, 256, 0, stream>>>(Qb, pos);
        rope_kernel<<<(BATCH * SEQ * HEADS * 16) / 256, 256, 0, stream>>>(Kb, pos);

        attn_kernel<<<ga, 256, 0, stream>>>(Qb, Kb, Vb, seg, Qb /* in-place */);

        gemm_lds<float><<<gg, 256, 0, stream>>>(Qb, Wob, out, (int)NTOK, HID, HID);
    } else if (ws_size >= 4 * MAT * sizeof(unsigned short)) {
        cvt_kernel<<<(int)(MAT / (256 * 8)), 256, 0, stream>>>(X, Xb);
        gemm_bt<true, false, unsigned short><<<gg, 256, 0, stream>>>((const void*)Xb, (const void*)wq, Qb, (int)NTOK, HID, HID);
        gemm_bt<true, false, unsigned short><<<gg, 256, 0, stream>>>((const void*)Xb, (const void*)wk, Kb, (int)NTOK, HID, HID);
        gemm_bt<true, false, unsigned short><<<gg, 256, 0, stream>>>((const void*)Xb, (const void*)wv, Vb, (int)NTOK, HID, HID);

        rope_kernel<<<(BATCH * SEQ * HEADS * 16) / 256, 256, 0, stream>>>(Qb, pos);
        rope_kernel<<<(BATCH * SEQ * HEADS * 16) / 256, 256, 0, stream>>>(Kb, pos);

        attn_kernel<<<ga, 256, 0, stream>>>(Qb, Kb, Vb, seg, Qb);

        gemm_bt<true, false, float><<<gg, 256, 0, stream>>>((const void*)Qb, (const void*)wo, out, (int)NTOK, HID, HID);
    } else {
        gemm_bt<false, false, unsigned short><<<gg, 256, 0, stream>>>((const void*)X, (const void*)wq, Qb, (int)NTOK, HID, HID);
        gemm_bt<false, false, unsigned short><<<gg, 256, 0, stream>>>((const void*)X, (const void*)wk, Kb, (int)NTOK, HID, HID);
        gemm_bt<false, false, unsigned short><<<gg, 256, 0, stream>>>((const void*)X, (const void*)wv, Vb, (int)NTOK, HID, HID);

        rope_kernel<<<(BATCH * SEQ * HEADS * 16) / 256, 256, 0, stream>>>(Qb, pos);
        rope_kernel<<<(BATCH * SEQ * HEADS * 16) / 256, 256, 0, stream>>>(Kb, pos);

        attn_kernel<<<ga, 256, 0, stream>>>(Qb, Kb, Vb, seg, Qb);

        gemm_bt<true, false, float><<<gg, 256, 0, stream>>>((const void*)Qb, (const void*)wo, out, (int)NTOK, HID, HID);
    }
}